// Round 1
// baseline (5171.927 us; speedup 1.0000x reference)
//
#include <hip/hip_runtime.h>

// RNN scan: h[t] = tanh(W_h h[t-1] + W_x x[t] + b), out = stacked h.
// Plan:
//  prep_kernel : transpose W_x -> wxT (fp32), extract bias, pack W_h -> f16
//                (layout Whpk[k8][r] = 8 consecutive-k halves of row r, 16B).
//  xin_gemm    : fp32 tiled GEMM writes u[t,b,h] = x.W_x^T + b INTO d_out.
//  rnn_scan    : 64 wgs (one per batch elem), 512 thr; thread r owns row r.
//                W_h f16: first 7/64 cached in LDS (56KiB), rest streamed
//                from L2 each step. v_dot2_f32_f16 accumulate, fp32 state
//                written in-place over u in d_out.

typedef _Float16 h2 __attribute__((ext_vector_type(2)));

#define T_STEPS 1024
#define B_SZ    64
#define NIN     128
#define NH      512
#define WCOLS   641        // NH + NIN + 1
#define NC      7          // k8-groups of W_h cached in LDS (7*512*16B = 56KiB)

__device__ __forceinline__ float fdot2_(h2 a, h2 b, float c) {
#if __has_builtin(__builtin_amdgcn_fdot2)
    return __builtin_amdgcn_fdot2(a, b, c, false);
#else
    return c + (float)a.x * (float)b.x + (float)a.y * (float)b.y;
#endif
}

__device__ __forceinline__ float dot8(uint4 wu, uint4 hu, float acc) {
    union { uint4 u; h2 h[4]; } w, hv;
    w.u = wu; hv.u = hu;
    acc = fdot2_(w.h[0], hv.h[0], acc);
    acc = fdot2_(w.h[1], hv.h[1], acc);
    acc = fdot2_(w.h[2], hv.h[2], acc);
    acc = fdot2_(w.h[3], hv.h[3], acc);
    return acc;
}

// ---------------- prep: weight reshuffle ----------------
__global__ void prep_kernel(const float* __restrict__ w_rec,
                            float* __restrict__ wxT,
                            float* __restrict__ bias,
                            uint4* __restrict__ Whpk) {
    int g = blockIdx.x * 256 + threadIdx.x;
    if (g < NIN * NH) {                               // wxT[i*512+h] = w_x[h][i]
        int i = g >> 9, h = g & (NH - 1);
        wxT[g] = w_rec[h * WCOLS + NH + i];
    } else if (g < NIN * NH + 64 * NH) {              // pack W_h rows to f16
        int m = g - NIN * NH;
        int p4 = m >> 9, r = m & (NH - 1);
        union { uint4 u; _Float16 f[8]; } pk;
#pragma unroll
        for (int j = 0; j < 8; ++j)
            pk.f[j] = (_Float16)w_rec[r * WCOLS + p4 * 8 + j];
        Whpk[p4 * NH + r] = pk.u;
    } else if (g < NIN * NH + 64 * NH + NH) {         // bias
        int h = g - (NIN * NH + 64 * NH);
        bias[h] = w_rec[h * WCOLS + NH + NIN];
    }
}

// ---------------- xin GEMM: u = x @ W_x^T + b -> d_out ----------------
// block tile 128(tb) x 128(h), K=128 in 4 chunks of 32; 8x8 per thread.
__global__ __launch_bounds__(256) void xin_gemm(const float* __restrict__ x,
                                                const float* __restrict__ wxT,
                                                const float* __restrict__ bias,
                                                float* __restrict__ out) {
    __shared__ float4 xl[128 * 8];    // [row][c4] 16 KiB
    __shared__ float4 wl[32 * 32];    // [i][c4]   16 KiB
    __shared__ float  bs[128];
    const int tid = threadIdx.x;
    const int tb0 = blockIdx.x * 128;
    const int hc0 = blockIdx.y * 128;
    if (tid < 128) bs[tid] = bias[hc0 + tid];
    const int tx = tid & 15, ty = tid >> 4;

    float acc[8][8];
#pragma unroll
    for (int r = 0; r < 8; ++r)
#pragma unroll
        for (int c = 0; c < 8; ++c) acc[r][c] = 0.f;

    for (int kc = 0; kc < 4; ++kc) {
        __syncthreads();
#pragma unroll
        for (int l = 0; l < 4; ++l) {                 // x chunk 128x32
            int idx = tid + 256 * l;
            int row = idx >> 3, c4 = idx & 7;
            xl[idx] = *(const float4*)(x + (long)(tb0 + row) * NIN + kc * 32 + c4 * 4);
        }
#pragma unroll
        for (int l = 0; l < 4; ++l) {                 // w chunk 32x128
            int idx = tid + 256 * l;
            int ii = idx >> 5, c4 = idx & 31;
            wl[idx] = *(const float4*)(wxT + (kc * 32 + ii) * NH + hc0 + c4 * 4);
        }
        __syncthreads();
#pragma unroll
        for (int i4 = 0; i4 < 8; ++i4) {
            float4 xv[8];
#pragma unroll
            for (int rr = 0; rr < 8; ++rr) xv[rr] = xl[(ty * 8 + rr) * 8 + i4];
#pragma unroll
            for (int j = 0; j < 4; ++j) {
                float4 w0 = wl[(i4 * 4 + j) * 32 + tx * 2];
                float4 w1 = wl[(i4 * 4 + j) * 32 + tx * 2 + 1];
#pragma unroll
                for (int rr = 0; rr < 8; ++rr) {
                    float xs = (j == 0) ? xv[rr].x : (j == 1) ? xv[rr].y
                             : (j == 2) ? xv[rr].z : xv[rr].w;
                    acc[rr][0] += xs * w0.x; acc[rr][1] += xs * w0.y;
                    acc[rr][2] += xs * w0.z; acc[rr][3] += xs * w0.w;
                    acc[rr][4] += xs * w1.x; acc[rr][5] += xs * w1.y;
                    acc[rr][6] += xs * w1.z; acc[rr][7] += xs * w1.w;
                }
            }
        }
    }
#pragma unroll
    for (int rr = 0; rr < 8; ++rr) {
        long row = tb0 + ty * 8 + rr;
        float4 o0, o1;
        o0.x = acc[rr][0] + bs[tx * 8 + 0]; o0.y = acc[rr][1] + bs[tx * 8 + 1];
        o0.z = acc[rr][2] + bs[tx * 8 + 2]; o0.w = acc[rr][3] + bs[tx * 8 + 3];
        o1.x = acc[rr][4] + bs[tx * 8 + 4]; o1.y = acc[rr][5] + bs[tx * 8 + 5];
        o1.z = acc[rr][6] + bs[tx * 8 + 6]; o1.w = acc[rr][7] + bs[tx * 8 + 7];
        *(float4*)(out + row * NH + hc0 + tx * 8)     = o0;
        *(float4*)(out + row * NH + hc0 + tx * 8 + 4) = o1;
    }
}

// ---------------- serial scan: one workgroup per batch element ----------------
__global__ __launch_bounds__(512) void rnn_scan(float* __restrict__ out,
                                                const float* __restrict__ h0,
                                                const uint4* __restrict__ Whpk) {
    __shared__ uint4 Wl[NC * NH];   // 56 KiB: W_h rows, k8-groups 0..NC-1
    __shared__ uint4 hh4[NH / 8];   // 1 KiB: h state as 512 f16

    const int tid = threadIdx.x;    // = output row r
    const int b   = blockIdx.x;

#pragma unroll
    for (int j = 0; j < NC; ++j) Wl[j * NH + tid] = Whpk[j * NH + tid];
    ((_Float16*)hh4)[tid] = (_Float16)h0[b * NH + tid];
    __syncthreads();

    float* pu = out + (long)b * NH + tid;   // u/h slot for (t=0, b, r)

    for (int t = 0; t < T_STEPS; ++t) {
        float a0 = *pu;            // u = xin (written by xin_gemm), in place
        float a1 = 0.f;
#pragma unroll
        for (int p4 = 0; p4 < NC; ++p4) {          // LDS-cached part
            uint4 w  = Wl[p4 * NH + tid];
            uint4 hv = hh4[p4];
            if (p4 & 1) a1 = dot8(w, hv, a1); else a0 = dot8(w, hv, a0);
        }
#pragma unroll 4
        for (int p4 = NC; p4 < 64; ++p4) {         // L2-streamed part
            uint4 w  = Whpk[p4 * NH + tid];
            uint4 hv = hh4[p4];
            if (p4 & 1) a1 = dot8(w, hv, a1); else a0 = dot8(w, hv, a0);
        }
        float hnew = tanhf(a0 + a1);
        *pu = hnew;                                 // fp32 output
        __syncthreads();                            // all reads of hh4 done
        ((_Float16*)hh4)[tid] = (_Float16)hnew;     // publish f16 state
        __syncthreads();
        pu += B_SZ * NH;
    }
}

extern "C" void kernel_launch(void* const* d_in, const int* in_sizes, int n_in,
                              void* d_out, int out_size, void* d_ws, size_t ws_size,
                              hipStream_t stream) {
    const float* x     = (const float*)d_in[0];   // (1024,64,128)
    const float* h0    = (const float*)d_in[1];   // (64,512)
    const float* w_rec = (const float*)d_in[2];   // (512,641)
    float* out = (float*)d_out;                   // (1024,64,512)

    // workspace layout: wxT (256 KiB) | bias (2 KiB) | Whpk f16 (512 KiB)
    float* wxT  = (float*)d_ws;
    float* bias = wxT + NIN * NH;
    uint4* Whpk = (uint4*)((char*)d_ws + (NIN * NH + NH) * sizeof(float)); // 264192, 16B aligned

    prep_kernel<<<387, 256, 0, stream>>>(w_rec, wxT, bias, Whpk);

    dim3 gA(T_STEPS * B_SZ / 128, NH / 128);      // 512 x 4
    xin_gemm<<<gA, 256, 0, stream>>>(x, wxT, bias, out);

    rnn_scan<<<B_SZ, NH, 0, stream>>>(out, h0, Whpk);
}

// Round 2
// 2710.003 us; speedup vs baseline: 1.9085x; 1.9085x over previous
//
#include <hip/hip_runtime.h>

// RNN scan: h[t] = tanh(W_h h[t-1] + W_x x[t] + b), out = stacked h.
//  prep_kernel : transpose W_x -> wxT (fp32), extract bias, pack W_h -> f16
//                (Whpk[k8][r] = 8 consecutive-k halves of row r, 16B).
//  xin_gemm    : fp32 tiled GEMM writes u[t,b,h] = x.W_x^T + b INTO d_out.
//  rnn_scan    : 64 wgs (one per batch elem), 512 thr; thread r owns row r.
//                W_h f16 split: 7 k8-groups in LDS, 36 in REGISTERS (144
//                VGPRs), 21 streamed from L2 in 3 pipelined chunks of 7.
//                u[t+1] prefetched a full step ahead; double-buffered h
//                state -> single barrier/step. Fast tanh via v_exp_f32.

typedef _Float16 h2 __attribute__((ext_vector_type(2)));

#define T_STEPS 1024
#define B_SZ    64
#define NIN     128
#define NH      512
#define WCOLS   641        // NH + NIN + 1
#define LCACHE  7          // k8-groups in LDS (7*512*16B = 56 KiB)
#define RCACHE  36         // k8-groups in registers (144 VGPRs)
// group map: LDS = 0..6, REG = 7..42, STREAM = 43..63 (21 groups)

__device__ __forceinline__ float fdot2_(h2 a, h2 b, float c) {
#if __has_builtin(__builtin_amdgcn_fdot2)
    return __builtin_amdgcn_fdot2(a, b, c, false);
#else
    return c + (float)a.x * (float)b.x + (float)a.y * (float)b.y;
#endif
}

__device__ __forceinline__ float dot8(uint4 wu, uint4 hu, float acc) {
    union { uint4 u; h2 h[4]; } w, hv;
    w.u = wu; hv.u = hu;
    acc = fdot2_(w.h[0], hv.h[0], acc);
    acc = fdot2_(w.h[1], hv.h[1], acc);
    acc = fdot2_(w.h[2], hv.h[2], acc);
    acc = fdot2_(w.h[3], hv.h[3], acc);
    return acc;
}

__device__ __forceinline__ float fast_tanh(float x) {
    // tanh(x) = 1 - 2/(exp2(x * 2/ln2) + 1); monotone-safe at +-inf
    float z = x * 2.8853900817779268f;
#if __has_builtin(__builtin_amdgcn_exp2f)
    float e = __builtin_amdgcn_exp2f(z);
#else
    float e = exp2f(z);
#endif
#if __has_builtin(__builtin_amdgcn_rcpf)
    return 1.f - 2.f * __builtin_amdgcn_rcpf(e + 1.f);
#else
    return 1.f - 2.f / (e + 1.f);
#endif
}

// ---------------- prep: weight reshuffle ----------------
__global__ void prep_kernel(const float* __restrict__ w_rec,
                            float* __restrict__ wxT,
                            float* __restrict__ bias,
                            uint4* __restrict__ Whpk) {
    int g = blockIdx.x * 256 + threadIdx.x;
    if (g < NIN * NH) {                               // wxT[i*512+h] = w_x[h][i]
        int i = g >> 9, h = g & (NH - 1);
        wxT[g] = w_rec[h * WCOLS + NH + i];
    } else if (g < NIN * NH + 64 * NH) {              // pack W_h rows to f16
        int m = g - NIN * NH;
        int p4 = m >> 9, r = m & (NH - 1);
        union { uint4 u; _Float16 f[8]; } pk;
#pragma unroll
        for (int j = 0; j < 8; ++j)
            pk.f[j] = (_Float16)w_rec[r * WCOLS + p4 * 8 + j];
        Whpk[p4 * NH + r] = pk.u;
    } else if (g < NIN * NH + 64 * NH + NH) {         // bias
        int h = g - (NIN * NH + 64 * NH);
        bias[h] = w_rec[h * WCOLS + NH + NIN];
    }
}

// ---------------- xin GEMM: u = x @ W_x^T + b -> d_out ----------------
__global__ __launch_bounds__(256) void xin_gemm(const float* __restrict__ x,
                                                const float* __restrict__ wxT,
                                                const float* __restrict__ bias,
                                                float* __restrict__ out) {
    __shared__ float4 xl[128 * 8];    // [row][c4] 16 KiB
    __shared__ float4 wl[32 * 32];    // [i][c4]   16 KiB
    __shared__ float  bs[128];
    const int tid = threadIdx.x;
    const int tb0 = blockIdx.x * 128;
    const int hc0 = blockIdx.y * 128;
    if (tid < 128) bs[tid] = bias[hc0 + tid];
    const int tx = tid & 15, ty = tid >> 4;

    float acc[8][8];
#pragma unroll
    for (int r = 0; r < 8; ++r)
#pragma unroll
        for (int c = 0; c < 8; ++c) acc[r][c] = 0.f;

    for (int kc = 0; kc < 4; ++kc) {
        __syncthreads();
#pragma unroll
        for (int l = 0; l < 4; ++l) {                 // x chunk 128x32
            int idx = tid + 256 * l;
            int row = idx >> 3, c4 = idx & 7;
            xl[idx] = *(const float4*)(x + (long)(tb0 + row) * NIN + kc * 32 + c4 * 4);
        }
#pragma unroll
        for (int l = 0; l < 4; ++l) {                 // w chunk 32x128
            int idx = tid + 256 * l;
            int ii = idx >> 5, c4 = idx & 31;
            wl[idx] = *(const float4*)(wxT + (kc * 32 + ii) * NH + hc0 + c4 * 4);
        }
        __syncthreads();
#pragma unroll
        for (int i4 = 0; i4 < 8; ++i4) {
            float4 xv[8];
#pragma unroll
            for (int rr = 0; rr < 8; ++rr) xv[rr] = xl[(ty * 8 + rr) * 8 + i4];
#pragma unroll
            for (int j = 0; j < 4; ++j) {
                float4 w0 = wl[(i4 * 4 + j) * 32 + tx * 2];
                float4 w1 = wl[(i4 * 4 + j) * 32 + tx * 2 + 1];
#pragma unroll
                for (int rr = 0; rr < 8; ++rr) {
                    float xs = (j == 0) ? xv[rr].x : (j == 1) ? xv[rr].y
                             : (j == 2) ? xv[rr].z : xv[rr].w;
                    acc[rr][0] += xs * w0.x; acc[rr][1] += xs * w0.y;
                    acc[rr][2] += xs * w0.z; acc[rr][3] += xs * w0.w;
                    acc[rr][4] += xs * w1.x; acc[rr][5] += xs * w1.y;
                    acc[rr][6] += xs * w1.z; acc[rr][7] += xs * w1.w;
                }
            }
        }
    }
#pragma unroll
    for (int rr = 0; rr < 8; ++rr) {
        long row = tb0 + ty * 8 + rr;
        float4 o0, o1;
        o0.x = acc[rr][0] + bs[tx * 8 + 0]; o0.y = acc[rr][1] + bs[tx * 8 + 1];
        o0.z = acc[rr][2] + bs[tx * 8 + 2]; o0.w = acc[rr][3] + bs[tx * 8 + 3];
        o1.x = acc[rr][4] + bs[tx * 8 + 4]; o1.y = acc[rr][5] + bs[tx * 8 + 5];
        o1.z = acc[rr][6] + bs[tx * 8 + 6]; o1.w = acc[rr][7] + bs[tx * 8 + 7];
        *(float4*)(out + row * NH + hc0 + tx * 8)     = o0;
        *(float4*)(out + row * NH + hc0 + tx * 8 + 4) = o1;
    }
}

// ---------------- serial scan: one workgroup per batch element ----------------
// __launch_bounds__(512, 2): 8 waves must co-reside (one wg/CU), caps VGPR<=256.
__global__ __launch_bounds__(512, 2) void rnn_scan(float* __restrict__ out,
                                                   const float* __restrict__ h0,
                                                   const uint4* __restrict__ Whpk) {
    __shared__ uint4 Wl[LCACHE * NH];   // 56 KiB
    __shared__ uint4 hh[2][NH / 8];     // double-buffered f16 h state, 2 KiB

    const int tid = threadIdx.x;        // = output row r
    const int b   = blockIdx.x;

#pragma unroll
    for (int j = 0; j < LCACHE; ++j) Wl[j * NH + tid] = Whpk[j * NH + tid];

    uint4 Wreg[RCACHE];                 // groups 7..42 live in registers
#pragma unroll
    for (int i = 0; i < RCACHE; ++i) Wreg[i] = Whpk[(LCACHE + i) * NH + tid];

    ((_Float16*)hh[0])[tid] = (_Float16)h0[b * NH + tid];
    __syncthreads();

    float* pu = out + (long)b * NH + tid;   // u/h slot for (t, b, r)
    float u_cur = *pu;                      // u for t=0

    for (int t = 0; t < T_STEPS; ++t) {
        const uint4* hcur = hh[t & 1];
        float acc[4];
        acc[0] = u_cur; acc[1] = 0.f; acc[2] = 0.f; acc[3] = 0.f;

        uint4 bufA[7], bufB[7];
        // issue stream chunk A: groups 43..49
#pragma unroll
        for (int i = 0; i < 7; ++i) bufA[i] = Whpk[(43 + i) * NH + tid];
        // prefetch next step's u (in-bounds clamp; value unused at t=1023)
        {
            long stride = (t + 1 < T_STEPS) ? (long)B_SZ * NH : 0;
            u_cur = pu[stride];
        }
        // register groups 7..24 while chunk A is in flight
#pragma unroll
        for (int i = 0; i < 18; ++i)
            acc[i & 3] = dot8(Wreg[i], hcur[LCACHE + i], acc[i & 3]);
        // issue chunk B: groups 50..56; consume A
#pragma unroll
        for (int i = 0; i < 7; ++i) bufB[i] = Whpk[(50 + i) * NH + tid];
#pragma unroll
        for (int i = 0; i < 7; ++i)
            acc[i & 3] = dot8(bufA[i], hcur[43 + i], acc[i & 3]);
        // register groups 25..42
#pragma unroll
        for (int i = 18; i < 36; ++i)
            acc[i & 3] = dot8(Wreg[i], hcur[LCACHE + i], acc[i & 3]);
        // issue chunk C: groups 57..63; consume B
#pragma unroll
        for (int i = 0; i < 7; ++i) bufA[i] = Whpk[(57 + i) * NH + tid];
#pragma unroll
        for (int i = 0; i < 7; ++i)
            acc[i & 3] = dot8(bufB[i], hcur[50 + i], acc[i & 3]);
        // LDS groups 0..6
#pragma unroll
        for (int i = 0; i < 7; ++i)
            acc[i & 3] = dot8(Wl[i * NH + tid], hcur[i], acc[i & 3]);
        // consume C
#pragma unroll
        for (int i = 0; i < 7; ++i)
            acc[i & 3] = dot8(bufA[i], hcur[57 + i], acc[i & 3]);

        float hnew = fast_tanh((acc[0] + acc[1]) + (acc[2] + acc[3]));
        *pu = hnew;                                   // fp32 output (in place)
        ((_Float16*)hh[(t + 1) & 1])[tid] = (_Float16)hnew;  // publish f16 state
        pu += B_SZ * NH;
        __syncthreads();   // writes to hh[(t+1)&1] visible; reads of hcur done
    }
}

extern "C" void kernel_launch(void* const* d_in, const int* in_sizes, int n_in,
                              void* d_out, int out_size, void* d_ws, size_t ws_size,
                              hipStream_t stream) {
    const float* x     = (const float*)d_in[0];   // (1024,64,128)
    const float* h0    = (const float*)d_in[1];   // (64,512)
    const float* w_rec = (const float*)d_in[2];   // (512,641)
    float* out = (float*)d_out;                   // (1024,64,512)

    // workspace layout: wxT (256 KiB) | bias (2 KiB) | Whpk f16 (512 KiB)
    float* wxT  = (float*)d_ws;
    float* bias = wxT + NIN * NH;
    uint4* Whpk = (uint4*)((char*)d_ws + (NIN * NH + NH) * sizeof(float)); // 16B aligned

    prep_kernel<<<387, 256, 0, stream>>>(w_rec, wxT, bias, Whpk);

    dim3 gA(T_STEPS * B_SZ / 128, NH / 128);      // 512 x 4
    xin_gemm<<<gA, 256, 0, stream>>>(x, wxT, bias, out);

    rnn_scan<<<B_SZ, NH, 0, stream>>>(out, h0, Whpk);
}